// Round 1
// 158.829 us; speedup vs baseline: 1.0002x; 1.0002x over previous
//
#include <hip/hip_runtime.h>
#include <hip/hip_bf16.h>

// B=8, Ct=256, Cs=128, H=W=32, S=1024, E=256, nH=8, hd=32
typedef unsigned short u16;
typedef unsigned int u32;
typedef __attribute__((ext_vector_type(8))) short short8;
typedef __attribute__((ext_vector_type(4))) float f32x4;
typedef __attribute__((ext_vector_type(4))) unsigned short u16x4;
typedef __attribute__((ext_vector_type(4))) int i32x4;

static __device__ __forceinline__ u16 f2bf(float x) {
  __hip_bfloat16 b = __float2bfloat16(x);
  return *reinterpret_cast<u16*>(&b);
}
static __device__ __forceinline__ u32 fbits(float x) {
  union { float f; u32 u; } v; v.f = x; return v.u;
}
// pack two f32 -> two truncated bf16 in one dword
static __device__ __forceinline__ u32 pk_trunc(float lo, float hi) {
  return __builtin_amdgcn_perm(fbits(hi), fbits(lo), 0x07060302u);
}
// async global->LDS, 16B per lane; dest = lds base (wave-uniform) + lane*16
static __device__ __forceinline__ void gl2lds16(const u16* g, u16* l) {
  __builtin_amdgcn_global_load_lds(
      (const __attribute__((address_space(1))) void*)g,
      (__attribute__((address_space(3))) void*)l, 16, 0, 0);
}

// 1/sqrt(32) * log2(e)  (exp2-based softmax)
#define QSCALE2 (0.17677669529663687f * 1.4426950408889634f)

// ---------------------------------------------------------------------------
// Merged prep + register-transpose-cast + attn_out zero. (unchanged)
// ---------------------------------------------------------------------------
__global__ __launch_bounds__(256) void prep_xpose(
    const float* __restrict__ in_proj_w, const float* __restrict__ in_proj_b,
    const float* __restrict__ kv_w, const float* __restrict__ fuse_w,
    const float* __restrict__ out_proj_w, const float* __restrict__ out_proj_b,
    const float* __restrict__ gamma, const float* __restrict__ beta,
    const float* __restrict__ mean, const float* __restrict__ var,
    const float* __restrict__ tgt, const float* __restrict__ src,
    u16* __restrict__ WqB, u16* __restrict__ WkvB, u16* __restrict__ M2B,
    float* __restrict__ qbias, float2* __restrict__ bnpk,
    u16* __restrict__ tgtT, u16* __restrict__ srcT,
    float* __restrict__ attn_out) {
  if (blockIdx.x >= 1537) {
    int i = (blockIdx.x - 1537) * 256 + threadIdx.x;
    attn_out[i] = 0.f;
    return;
  }
  if (blockIdx.x < 769) {
    int idx = blockIdx.x * 256 + threadIdx.x;
    if (idx < 65536) {
      WqB[idx] = f2bf(in_proj_w[idx] * QSCALE2);
    } else if (idx < 131072) {
      int i = idx - 65536;
      int m = i >> 7, c = i & 127;
      const float* wrow = in_proj_w + (size_t)(256 + m) * 256;
      float s = 0.f;
      for (int e2 = 0; e2 < 256; ++e2) s += wrow[e2] * kv_w[e2 * 128 + c];
      WkvB[i] = f2bf(s);
    } else if (idx < 196608) {
      int i = idx - 131072;
      int c = i >> 8, e2 = i & 255;
      float s = 0.f;
      for (int e = 0; e < 256; ++e)
        s += fuse_w[c * 256 + e] * out_proj_w[e * 256 + e2];
      M2B[i] = f2bf(s);
    } else if (idx < 196864) {
      int c = idx - 196608;
      float fbv = 0.f;
      for (int e = 0; e < 256; ++e) fbv += fuse_w[c * 256 + e] * out_proj_b[e];
      float inv = gamma[c] * rsqrtf(var[c] + 1e-5f);
      bnpk[c] = make_float2(inv, (fbv - mean[c]) * inv + beta[c]);
      qbias[c] = in_proj_b[c] * QSCALE2;
    }
    return;
  }
  // ---- xpose part: register 4x4 transpose-cast ----
  int i0 = blockIdx.x - 769;
  int b = i0 / 96, rem = i0 % 96;
  int by = rem >> 4, sb = (rem & 15) * 64;
  const float* X;
  u16* XT;
  int C, cb;
  if (by < 4) {
    X = tgt + (size_t)b * 256 * 1024;
    XT = tgtT + (size_t)b * 1024 * 256;
    C = 256;
    cb = by * 64;
  } else {
    X = src + (size_t)b * 128 * 1024;
    XT = srcT + (size_t)b * 1024 * 128;
    C = 128;
    cb = (by - 4) * 64;
  }
  int t = threadIdx.x;
  int c = cb + (t >> 4) * 4;
  int s = sb + (t & 15) * 4;
  const float* Xp = X + (size_t)c * 1024 + s;
  float4 r0 = *(const float4*)(Xp);
  float4 r1 = *(const float4*)(Xp + 1024);
  float4 r2 = *(const float4*)(Xp + 2048);
  float4 r3 = *(const float4*)(Xp + 3072);
  u16* XTp = XT + (size_t)s * C + c;
  u16x4 o;
  o[0] = f2bf(r0.x); o[1] = f2bf(r1.x); o[2] = f2bf(r2.x); o[3] = f2bf(r3.x);
  *(u16x4*)(XTp) = o;
  o[0] = f2bf(r0.y); o[1] = f2bf(r1.y); o[2] = f2bf(r2.y); o[3] = f2bf(r3.y);
  *(u16x4*)(XTp + C) = o;
  o[0] = f2bf(r0.z); o[1] = f2bf(r1.z); o[2] = f2bf(r2.z); o[3] = f2bf(r3.z);
  *(u16x4*)(XTp + 2 * C) = o;
  o[0] = f2bf(r0.w); o[1] = f2bf(r1.w); o[2] = f2bf(r2.w); o[3] = f2bf(r3.w);
  *(u16x4*)(XTp + 3 * C) = o;
}

// ---------------------------------------------------------------------------
// QKV projection: now double-buffered LDS + 2-phase prefetch (issue next
// stage before compute; single barrier per K-step). Layouts unchanged.
// grid (8,12,8). Tile 64m x 128n. LDS 24KB -> still 4 blocks/CU.
// ---------------------------------------------------------------------------
__global__ __launch_bounds__(256, 4) void qkv_gemm(
    const u16* __restrict__ tgtT, const u16* __restrict__ srcT,
    const u16* __restrict__ WqB, const u16* __restrict__ WkvB,
    const float* __restrict__ qbias, const float* __restrict__ bkv,
    u16* __restrict__ QB, u16* __restrict__ KB, u16* __restrict__ VB) {
  __shared__ __align__(16) u16 Wl[2][64 * 32];   // 8KB
  __shared__ __align__(16) u16 Xl[2][128 * 32];  // 16KB
  int b = blockIdx.z, my = blockIdx.y, n0 = blockIdx.x * 128;
  bool isQ = my < 4;
  int m0 = isQ ? my * 64 : (my - 4) * 64;
  int Kd = isQ ? 256 : 128;
  const u16* Wp = isQ ? WqB : WkvB;
  const u16* Xp = isQ ? tgtT + (size_t)b * 1024 * 256
                      : srcT + (size_t)b * 1024 * 128;
  int t = threadIdx.x, wave = t >> 6, lane = t & 63;
  int lq = lane & 15, quad = lane >> 4;
  int srow = t >> 2, sseg = t & 3;
  f32x4 acc[4][2];
#pragma unroll
  for (int mt = 0; mt < 4; ++mt)
#pragma unroll
    for (int nt = 0; nt < 2; ++nt) acc[mt][nt] = (f32x4){0.f, 0.f, 0.f, 0.f};

  int nk = Kd >> 5;
  // prologue: stage k-step 0 into buffer 0
  gl2lds16(&Wp[(size_t)(m0 + srow) * Kd + sseg * 8], &Wl[0][wave * 512]);
  gl2lds16(&Xp[(size_t)(n0 + srow) * Kd + sseg * 8], &Xl[0][wave * 512]);
  gl2lds16(&Xp[(size_t)(n0 + 64 + srow) * Kd + sseg * 8],
           &Xl[0][2048 + wave * 512]);
  __syncthreads();
  for (int kk = 0; kk < nk; ++kk) {
    int bsel = kk & 1;
    if (kk + 1 < nk) {  // prefetch next k-step into other buffer
      int k0 = (kk + 1) << 5;
      gl2lds16(&Wp[(size_t)(m0 + srow) * Kd + k0 + sseg * 8],
               &Wl[bsel ^ 1][wave * 512]);
      gl2lds16(&Xp[(size_t)(n0 + srow) * Kd + k0 + sseg * 8],
               &Xl[bsel ^ 1][wave * 512]);
      gl2lds16(&Xp[(size_t)(n0 + 64 + srow) * Kd + k0 + sseg * 8],
               &Xl[bsel ^ 1][2048 + wave * 512]);
    }
    short8 af[4], bfx[2];
#pragma unroll
    for (int mt = 0; mt < 4; ++mt)
      af[mt] = *(const short8*)&Wl[bsel][(mt * 16 + lq) * 32 + quad * 8];
#pragma unroll
    for (int nt = 0; nt < 2; ++nt)
      bfx[nt] = *(const short8*)&Xl[bsel][(wave * 32 + nt * 16 + lq) * 32 + quad * 8];
#pragma unroll
    for (int mt = 0; mt < 4; ++mt)
#pragma unroll
      for (int nt = 0; nt < 2; ++nt)
        acc[mt][nt] = __builtin_amdgcn_mfma_f32_16x16x32_bf16(af[mt], bfx[nt],
                                                              acc[mt][nt], 0, 0, 0);
    __syncthreads();  // implicit vmcnt(0): prefetched stage complete here
  }
  if (isQ) {
#pragma unroll
    for (int mt = 0; mt < 4; ++mt) {
      int e = m0 + mt * 16 + quad * 4;
      f32x4 bia = *(const f32x4*)&qbias[e];
      int hh = e >> 5, d0 = e & 31;
#pragma unroll
      for (int nt = 0; nt < 2; ++nt) {
        int n = n0 + wave * 32 + nt * 16 + lq;
        u16x4 pk;
#pragma unroll
        for (int r = 0; r < 4; ++r) pk[r] = f2bf(acc[mt][nt][r] + bia[r]);
        *(u16x4*)&QB[((size_t)(b * 8 + hh) * 1024 + n) * 32 + d0] = pk;
      }
    }
  } else {
#pragma unroll
    for (int mt = 0; mt < 4; ++mt) {
      int m = m0 + mt * 16 + quad * 4;
      f32x4 bia = *(const f32x4*)&bkv[m];
#pragma unroll
      for (int nt = 0; nt < 2; ++nt) {
        int n = n0 + wave * 32 + nt * 16 + lq;
        if (m < 256) {
          int hh = m >> 5, d = m & 31;
          u16x4 pk;
#pragma unroll
          for (int r = 0; r < 4; ++r) pk[r] = f2bf(acc[mt][nt][r] + bia[r]);
          *(u16x4*)&KB[((size_t)(b * 8 + hh) * 1024 + n) * 32 + d] = pk;
        } else {
          int e = m - 256;
#pragma unroll
          for (int r = 0; r < 4; ++r)
            VB[((size_t)b * 256 + e + r) * 1024 + n] = f2bf(acc[mt][nt][r] + bia[r]);
        }
      }
    }
  }
}

// ---------------------------------------------------------------------------
// Attention pass A: 128-key chunks, double-buffered K+V LDS (33KB total,
// keeps 4 blocks/CU), 2-phase prefetch. d<->lane mapping and all fragment
// layouts identical to the verified single-buffer version; V group pitch
// 544 u16 preserves the original +16-dword bank offset between groups.
// ---------------------------------------------------------------------------
static __device__ __forceinline__ void stage_kv(
    const u16* __restrict__ Kb, const u16* __restrict__ Vb, int c0,
    u16* __restrict__ Kl, u16* __restrict__ Vl,
    int wave, int lane, int srow, int sseg) {
#pragma unroll
  for (int i = 0; i < 2; ++i)
    gl2lds16(Kb + (size_t)(c0 + i * 64 + srow) * 32 + sseg * 8,
             Kl + i * 2048 + wave * 512);
#pragma unroll
  for (int i = 0; i < 2; ++i) {
    int g = wave * 2 + i;
    gl2lds16(Vb + (size_t)(g * 4 + (lane >> 4)) * 1024 + c0 + (lane & 15) * 8,
             Vl + g * 544);
  }
}

__global__ __launch_bounds__(256, 4) void attn_passA(
    const u16* __restrict__ QB, const u16* __restrict__ KB,
    const u16* __restrict__ VB, u16* __restrict__ ctxB,
    float* __restrict__ linv_ws) {
  __shared__ __align__(16) u16 Klds[2][128 * 32];  // 16KB
  __shared__ __align__(16) u16 Vlds[2][8 * 544];   // 17KB
  int bidx = blockIdx.x;
  int pair = bidx & 63, q0 = (bidx >> 6) * 64;
  int b = pair >> 3, h = pair & 7;
  int t = threadIdx.x, wave = t >> 6, lane = t & 63;
  int lq = lane & 15, quad = lane >> 4;
  int srow = t >> 2, sseg = t & 3;

  const u16* Qb = QB + (size_t)pair * 1024 * 32;
  const u16* Kb = KB + (size_t)pair * 1024 * 32;
  const u16* Vb = VB + (size_t)(b * 256 + h * 32) * 1024;

  int myq = q0 + wave * 16 + lq;
  short8 qf = *(const short8*)(Qb + (size_t)myq * 32 + quad * 8);

  const f32x4 zf = (f32x4){0.f, 0.f, 0.f, 0.f};
  f32x4 O0 = zf, O1 = zf;
  float lsum = 0.f;
  int keyA = ((lq >> 2) << 3) | (lq & 3);

  stage_kv(Kb, Vb, 0, Klds[0], Vlds[0], wave, lane, srow, sseg);
  __syncthreads();
  for (int cc = 0; cc < 8; ++cc) {
    int bsel = cc & 1;
    if (cc < 7)  // prefetch next 128-key chunk while computing current
      stage_kv(Kb, Vb, (cc + 1) * 128, Klds[bsel ^ 1], Vlds[bsel ^ 1],
               wave, lane, srow, sseg);
#pragma unroll
    for (int pr = 0; pr < 4; ++pr) {
      short8 kf0 = *(const short8*)&Klds[bsel][(pr * 32 + keyA) * 32 + quad * 8];
      short8 kf1 = *(const short8*)&Klds[bsel][(pr * 32 + keyA + 4) * 32 + quad * 8];
      f32x4 s0 = __builtin_amdgcn_mfma_f32_16x16x32_bf16(kf0, qf, zf, 0, 0, 0);
      f32x4 s1 = __builtin_amdgcn_mfma_f32_16x16x32_bf16(kf1, qf, zf, 0, 0, 0);
      f32x4 e0, e1;
#pragma unroll
      for (int r = 0; r < 4; ++r) {
        e0[r] = exp2f(s0[r]);
        e1[r] = exp2f(s1[r]);
      }
      lsum += (e0[0] + e0[1]) + (e0[2] + e0[3]) +
              (e1[0] + e1[1]) + (e1[2] + e1[3]);
      i32x4 pi;
      pi[0] = (int)pk_trunc(e0[0], e0[1]);
      pi[1] = (int)pk_trunc(e0[2], e0[3]);
      pi[2] = (int)pk_trunc(e1[0], e1[1]);
      pi[3] = (int)pk_trunc(e1[2], e1[3]);
      short8 pf = *(short8*)&pi;
      short8 vf0 = *(const short8*)&Vlds[bsel][(lq >> 2) * 544 + (lq & 3) * 128 +
                                               pr * 32 + quad * 8];
      short8 vf1 = *(const short8*)&Vlds[bsel][(4 + (lq >> 2)) * 544 + (lq & 3) * 128 +
                                               pr * 32 + quad * 8];
      O0 = __builtin_amdgcn_mfma_f32_16x16x32_bf16(vf0, pf, O0, 0, 0, 0);
      O1 = __builtin_amdgcn_mfma_f32_16x16x32_bf16(vf1, pf, O1, 0, 0, 0);
    }
    __syncthreads();  // implicit vmcnt(0): prefetch landed, prev buffer free
  }

  lsum += __shfl_xor(lsum, 16);
  lsum += __shfl_xor(lsum, 32);
  float linv = 1.f / lsum;

  u16x4 pk0, pk1;
#pragma unroll
  for (int r = 0; r < 4; ++r) {
    pk0[r] = f2bf(O0[r] * linv);
    pk1[r] = f2bf(O1[r] * linv);
  }
  u16* crow = ctxB + ((size_t)b * 1024 + myq) * 256 + h * 32 + quad * 4;
  *(u16x4*)crow = pk0;
  *(u16x4*)(crow + 16) = pk1;
  if (quad == 0) linv_ws[(size_t)pair * 1024 + myq] = linv;
}

// ---------------------------------------------------------------------------
// Merged tail: fused out GEMM+BN+SiLU+residual (blocks [0,512), memory-bound,
// double-buffered) co-scheduled with colsum (blocks [512,1536), VALU-bound).
// Separate pipes overlap when co-resident. LDS 16KB union.
// ---------------------------------------------------------------------------
__global__ __launch_bounds__(256, 4) void tail_kernel(
    const u16* __restrict__ M2B, const u16* __restrict__ ctxB,
    const float* __restrict__ tgt, const float2* __restrict__ bnpk,
    float* __restrict__ y,
    const u16* __restrict__ QB, const u16* __restrict__ KB,
    const float* __restrict__ linv_ws, float* __restrict__ attn_out) {
  __shared__ __align__(16) u16 SH[8192];  // 16KB union
  int t = threadIdx.x, wave = t >> 6, lane = t & 63;
  int lq = lane & 15, quad = lane >> 4;
  int srow = t >> 2, sseg = t & 3;
  const f32x4 zf = (f32x4){0.f, 0.f, 0.f, 0.f};

  if (blockIdx.x >= 512) {
    // ---- colsum: key-owning blocks, register K-frags, stream Q/linv ----
    int bidx = blockIdx.x - 512;
    int pair = bidx & 63, k0 = (bidx >> 6) * 64;
    int b = pair >> 3;
    const u16* Qb = QB + (size_t)pair * 1024 * 32;
    const u16* Kb = KB + (size_t)pair * 1024 * 32;
    const float* lvp = linv_ws + (size_t)pair * 1024;

    gl2lds16(Kb + (size_t)(k0 + srow) * 32 + sseg * 8, &SH[wave * 512]);
    __syncthreads();

    short8 kf[4];
#pragma unroll
    for (int nt = 0; nt < 4; ++nt)
      kf[nt] = *(const short8*)&SH[(nt * 16 + lq) * 32 + quad * 8];

    float cs[4] = {0.f, 0.f, 0.f, 0.f};
    for (int g = 0; g < 16; ++g) {
      int qg = g * 64 + wave * 16;
      short8 qf = *(const short8*)(Qb + (size_t)(qg + lq) * 32 + quad * 8);
      f32x4 lv = *(const f32x4*)&lvp[qg + quad * 4];
#pragma unroll
      for (int nt = 0; nt < 4; ++nt) {
        f32x4 s = __builtin_amdgcn_mfma_f32_16x16x32_bf16(qf, kf[nt], zf, 0, 0, 0);
        cs[nt] += exp2f(s[0]) * lv[0] + exp2f(s[1]) * lv[1] +
                  exp2f(s[2]) * lv[2] + exp2f(s[3]) * lv[3];
      }
    }
#pragma unroll
    for (int nt = 0; nt < 4; ++nt) {
      float v = cs[nt];
      v += __shfl_xor(v, 16);
      v += __shfl_xor(v, 32);
      if (quad == 0)
        atomicAdd(&attn_out[b * 1024 + k0 + nt * 16 + lq], v * (1.f / 8192.f));
    }
    return;
  }

  // ---- fused out GEMM + BN + SiLU + residual, double-buffered ----
  int ii = blockIdx.x;
  int b = ii >> 6, c0 = ((ii >> 4) & 3) * 64, s0 = (ii & 15) * 64;
  // Al[bsel] at SH + bsel*2048, Bl[bsel] at SH + 4096 + bsel*2048
  f32x4 acc[4];
#pragma unroll
  for (int mt = 0; mt < 4; ++mt) acc[mt] = zf;

  gl2lds16(&M2B[(size_t)(c0 + srow) * 256 + sseg * 8], &SH[wave * 512]);
  gl2lds16(&ctxB[((size_t)b * 1024 + s0 + srow) * 256 + sseg * 8],
           &SH[4096 + wave * 512]);
  __syncthreads();
  for (int kk = 0; kk < 8; ++kk) {
    int bsel = kk & 1;
    if (kk < 7) {
      int k0 = (kk + 1) << 5;
      gl2lds16(&M2B[(size_t)(c0 + srow) * 256 + k0 + sseg * 8],
               &SH[(bsel ^ 1) * 2048 + wave * 512]);
      gl2lds16(&ctxB[((size_t)b * 1024 + s0 + srow) * 256 + k0 + sseg * 8],
               &SH[4096 + (bsel ^ 1) * 2048 + wave * 512]);
    }
    short8 bfx = *(const short8*)&SH[4096 + bsel * 2048 + (wave * 16 + lq) * 32 + quad * 8];
    short8 af[4];
#pragma unroll
    for (int mt = 0; mt < 4; ++mt)
      af[mt] = *(const short8*)&SH[bsel * 2048 + (mt * 16 + lq) * 32 + quad * 8];
#pragma unroll
    for (int mt = 0; mt < 4; ++mt)
      acc[mt] = __builtin_amdgcn_mfma_f32_16x16x32_bf16(af[mt], bfx, acc[mt], 0, 0, 0);
    __syncthreads();
  }
  int s = s0 + wave * 16 + lq;
#pragma unroll
  for (int mt = 0; mt < 4; ++mt) {
#pragma unroll
    for (int r = 0; r < 4; ++r) {
      int c = c0 + mt * 16 + quad * 4 + r;
      float2 p = bnpk[c];
      float bn = acc[mt][r] * p.x + p.y;
      float sig = 1.f / (1.f + __expf(-bn));
      size_t idx = ((size_t)b * 256 + c) * 1024 + s;
      y[idx] = tgt[idx] + bn * sig;
    }
  }
}

// ---------------------------------------------------------------------------
extern "C" void kernel_launch(void* const* d_in, const int* in_sizes, int n_in,
                              void* d_out, int out_size, void* d_ws, size_t ws_size,
                              hipStream_t stream) {
  const float* tgt = (const float*)d_in[0];
  const float* src = (const float*)d_in[1];
  const float* kv_w = (const float*)d_in[2];
  const float* in_proj_w = (const float*)d_in[3];
  const float* in_proj_b = (const float*)d_in[4];
  const float* out_proj_w = (const float*)d_in[5];
  const float* out_proj_b = (const float*)d_in[6];
  const float* fuse_w = (const float*)d_in[7];
  const float* bn_gamma = (const float*)d_in[8];
  const float* bn_beta = (const float*)d_in[9];
  const float* bn_mean = (const float*)d_in[10];
  const float* bn_var = (const float*)d_in[11];

  char* W = (char*)d_ws;
  u16* WqB = (u16*)W;                      // 128KB
  u16* WkvB = (u16*)(W + 131072);          // 128KB
  u16* M2B = (u16*)(W + 262144);           // 128KB
  float* qbias = (float*)(W + 393216);     // 1KB
  float2* bnpk = (float2*)(W + 394240);    // 2KB
  u16* tgtT = (u16*)(W + 397312);          // 4MB (B,S,256) bf16
  u16* srcT = tgtT + 2097152;              // 2MB (B,S,128) bf16
  u16* QB = srcT + 1048576;                // 4MB (B,nH,S,hd)
  u16* KB = QB + 2097152;                  // 4MB (B,nH,S,hd)
  u16* VB = KB + 2097152;                  // 4MB (B,E,S)
  u16* ctxB = VB + 2097152;                // 4MB (B,S,E)
  float* linv_ws = (float*)(ctxB + 2097152);  // 256KB (B,nH,S)

  float* y = (float*)d_out;
  float* attn_out = y + 2097152;

  prep_xpose<<<1569, 256, 0, stream>>>(in_proj_w, in_proj_b, kv_w, fuse_w,
                                       out_proj_w, out_proj_b, bn_gamma, bn_beta,
                                       bn_mean, bn_var, tgt, src,
                                       WqB, WkvB, M2B, qbias, bnpk, tgtT, srcT,
                                       attn_out);
  qkv_gemm<<<dim3(8, 12, 8), 256, 0, stream>>>(tgtT, srcT, WqB, WkvB, qbias,
                                               in_proj_b + 256, QB, KB, VB);
  attn_passA<<<1024, 256, 0, stream>>>(QB, KB, VB, ctxB, linv_ws);
  tail_kernel<<<1536, 256, 0, stream>>>(M2B, ctxB, tgt, bnpk, y,
                                        QB, KB, linv_ws, attn_out);
}